// Round 7
// baseline (768.640 us; speedup 1.0000x reference)
//
#include <hip/hip_runtime.h>
#include <hip/hip_fp16.h>
#include <stdint.h>

#define B_   16
#define T_   30
#define NF   480       // frames = B*T
#define NN   2048      // nodes
#define EE   32768     // edges
#define EPS  1e-5f

typedef unsigned int u32;
typedef unsigned short u16;
typedef __attribute__((ext_vector_type(8))) short short8;   // 8 bf16 = 4 VGPR
typedef __attribute__((ext_vector_type(4))) float f32x4;    // MFMA C/D frag

// ---------- helpers ----------
__device__ __forceinline__ u16 f2bf(float f) {           // RNE f32->bf16
  u32 u = __float_as_uint(f);
  u32 r = u + 0x7FFFu + ((u >> 16) & 1u);
  return (u16)(r >> 16);
}
__device__ __forceinline__ u32 pack2bf(float a, float b) {
  return (u32)f2bf(a) | ((u32)f2bf(b) << 16);
}
__device__ __forceinline__ float bflo(u32 w) { return __uint_as_float(w << 16); }
__device__ __forceinline__ float bfhi(u32 w) { return __uint_as_float(w & 0xFFFF0000u); }
__device__ __forceinline__ u16 f2h(float f) { return __half_as_ushort(__float2half(f)); }
__device__ __forceinline__ float h2f(u16 h) { return __half2float(__ushort_as_half(h)); }

// =========================================================================
// kPre: sort node_ids -> perm; degrees; rank dsts by length desc; rank-CSR
//       segments; counting-sort edges into rank-CSR in LDS; stream-out.
//       meta2[r] = { orig<<16 | len, seg<<16 | f16(dinv^2) }.
// =========================================================================
#define KP_KEYS  0        // u32[2048] [0,8192): keys; later scan aux
#define KP_HIST  8192     // u32[256]
#define KP_CUM   9216     // u32[256]
#define KP_CUR   10240    // u32[256]
#define KP_DEG   16384    // f32[2048] [16384,24576)
#define KP_REC   0        // overlay u32[32768] = [0,131072) at counting-sort
#define KP_DINVH 131072   // u16[2048] -> 135168
#define KP_CNT   135168   // u32[2048] -> 143360
#define KP_PR    143360   // u32[2048] perm<<16|rank -> 151552
#define KP_SEGR  151552   // u32[2048] lenR then segr -> 159744
#define KP_LDS   159744

__global__ __launch_bounds__(1024) void kPre(
    const int* __restrict__ ei, const float* __restrict__ ew, const int* __restrict__ nid,
    u32* __restrict__ recG, u32* __restrict__ meta2G)
{
  extern __shared__ unsigned char smem[];
  const int g = blockIdx.x, t = threadIdx.x;
  const int*   eig  = ei  + (size_t)g * 2 * EE;
  const float* ewg  = ew  + (size_t)g * EE;
  const int*   nidg = nid + (size_t)g * NN;

  u32*  keys  = (u32*)(smem + KP_KEYS);
  u32*  hist  = (u32*)(smem + KP_HIST);
  u32*  cum   = (u32*)(smem + KP_CUM);
  u32*  cur   = (u32*)(smem + KP_CUR);
  float* deg  = (float*)(smem + KP_DEG);
  u32*  rec   = (u32*)(smem + KP_REC);
  u16*  dinvh = (u16*)(smem + KP_DINVH);
  u32*  cnt   = (u32*)(smem + KP_CNT);
  u32*  pr    = (u32*)(smem + KP_PR);
  u32*  segr  = (u32*)(smem + KP_SEGR);
  u32*  m2f   = meta2G + (size_t)g * NN * 2;

  // stage 1: keys (stable: nid<<11 | idx), init
  keys[t]        = ((u32)nidg[t] << 11) | (u32)t;
  keys[t + 1024] = ((u32)nidg[t + 1024] << 11) | (u32)(t + 1024);
  deg[t] = 1.0f; deg[t + 1024] = 1.0f;
  cnt[t] = 0u; cnt[t + 1024] = 0u;
  __syncthreads();

  // bitonic sort
  for (int k = 2; k <= NN; k <<= 1) {
    for (int j = k >> 1; j > 0; j >>= 1) {
      int i = ((t & ~(j - 1)) << 1) | (t & (j - 1));
      int l = i | j;
      u32 x = keys[i], y = keys[l];
      bool up = ((i & k) == 0);
      if ((x > y) == up) { keys[i] = y; keys[l] = x; }
      __syncthreads();
    }
  }
  pr[2*t]   = (keys[2*t]   & 2047u) << 16;
  pr[2*t+1] = (keys[2*t+1] & 2047u) << 16;

  // stage 2: degree + per-dst count
  for (int e = t; e < EE; e += 1024) {
    int d = eig[EE + e];
    atomicAdd(&deg[d], ewg[e]);
    atomicAdd(&cnt[d], 1u);
  }
  __syncthreads();
  dinvh[2*t]   = f2h(rsqrtf(deg[2*t]));
  dinvh[2*t+1] = f2h(rsqrtf(deg[2*t+1]));

  // stage 3: 256-bucket length histogram -> descending-order bucket starts
  if (t < 256) hist[t] = 0u;
  __syncthreads();
  for (int i = t; i < NN; i += 1024) {
    u32 L = cnt[i];
    atomicAdd(&hist[L < 255u ? L : 255u], 1u);
  }
  __syncthreads();
  if (t < 256) cum[t] = hist[t];
  __syncthreads();
  for (int o = 1; o < 256; o <<= 1) {
    u32 v = 0u;
    if (t < 256 && t >= o) v = cum[t - o];
    __syncthreads();
    if (t < 256) cum[t] += v;
    __syncthreads();
  }
  if (t < 256) cur[t] = (u32)NN - cum[t];   // start of bucket (desc order)
  __syncthreads();

  // stage 4: rank assignment; lenR; meta word0
  for (int i = t; i < NN; i += 1024) {
    u32 L = cnt[i];
    u32 b = L < 255u ? L : 255u;
    u32 r = atomicAdd(&cur[b], 1u);
    u32 pv = pr[i] & 0xFFFF0000u;
    pr[i] = pv | r;
    segr[r] = L;                       // lenR
    m2f[2*r] = pv | L;                 // orig<<16 | len
  }
  __syncthreads();

  // stage 5: exclusive scan lenR -> segr (rank-CSR starts)
  {
    u32 c0 = segr[2*t], c1 = segr[2*t+1];
    u32* aux = keys;
    aux[t] = c0 + c1;
    __syncthreads();
    for (int o = 1; o < 1024; o <<= 1) {
      u32 v = (t >= o) ? aux[t - o] : 0u;
      __syncthreads();
      aux[t] += v;
      __syncthreads();
    }
    u32 base = (t == 0) ? 0u : aux[t - 1];
    segr[2*t] = base; segr[2*t+1] = base + c0;
  }
  __syncthreads();

  // stage 6: meta word1 = seg<<16 | f16(dinv^2)
  for (int i = t; i < NN; i += 1024) {
    u32 r = pr[i] & 0xFFFFu;
    float dv = h2f(dinvh[i]);
    m2f[2*r + 1] = (segr[r] << 16) | (u32)f2h(dv * dv);
  }
  cnt[t] = 0u; cnt[t + 1024] = 0u;
  __syncthreads();   // keys/hist/cum/cur/deg dead -> rec overlays [0,131072)

  // stage 7: counting-sort edges into rank-CSR
  for (int e = t; e < EE; e += 1024) {
    int s = eig[e], d = eig[EE + e];
    float nrm = h2f(dinvh[s]) * ewg[e] * h2f(dinvh[d]);
    u32 k = atomicAdd(&cnt[d], 1u);
    u32 pos = segr[pr[d] & 0xFFFFu] + k;
    rec[pos] = (pr[s] & 0xFFFF0000u) | (u32)f2h(nrm);   // src in ORIG x-row space
  }
  __syncthreads();

  // stream-out
  uint4* rg = (uint4*)(recG + (size_t)g * EE);
  const uint4* rl = (const uint4*)rec;
  for (int i = t; i < EE / 4; i += 1024) rg[i] = rl[i];
}

// =========================================================================
// kFuse v3: group-per-rank CSR walks (conflict-free LDS).
//   Phase A: 8-lane groups walk x (feat-per-lane) -> aggh f16[2048][8].
//   Per pass p (2 passes x 32 feats):
//     B: thread-per-rank h1 slice = agg@W1f + t1f, ReLU -> LDS [2048][32]
//        (rows keyed by orig, 16B units XOR-swizzled by (orig>>1)&3)
//     C: 16-lane groups walk h1 (2 feats/lane) -> agg2 half-plane out.
//   LDS 160KB: [0,131072) xs->h1 ; [131072,163840) aggh.
// =========================================================================
#define KF_LDS 163840

__global__ __launch_bounds__(1024, 4) void kFuse(
    const float* __restrict__ x, const u32* __restrict__ recG,
    const uint2* __restrict__ meta2G,
    const float* __restrict__ W1f, const float* __restrict__ t1f,
    u16* __restrict__ aggOut)
{
  extern __shared__ unsigned char smem[];
  u16*  h1   = (u16*)smem;                     // [2048][32] bf16 (phases B/C)
  float* xs  = (float*)smem;                   // [2048][8] f32 (phase A)
  u16*  aggh = (u16*)(smem + 131072);          // f16 [2048][8]
  const int g = blockIdx.x, t = threadIdx.x;
  const u32*  recf = recG + (size_t)g * EE;
  const uint2* m2f = meta2G + (size_t)g * NN;

  // stage x rows (orig order, coalesced)
  {
    const float4* xg = (const float4*)(x + (size_t)g * NN * 8);
    for (int i = t; i < NN * 2; i += 1024) ((float4*)xs)[i] = xg[i];
  }
  __syncthreads();

  // ---- phase A: walk-1, 8-lane groups, feat-per-lane ----
  {
    const int G8 = t >> 3, L8 = t & 7;
    for (int c = 0; c < 16; ++c) {
      int r = c * 128 + G8;
      uint2 m = m2f[r];
      int orig = (int)(m.x >> 16), len = (int)(m.x & 0xFFFFu);
      u32 seg = m.y >> 16;
      float dv2 = h2f((u16)(m.y & 0xFFFFu));
      float acc = dv2 * xs[orig * 8 + L8];
      int j = 0;
      for (; j + 4 <= len; j += 4) {
        u32 q0 = recf[seg+j], q1 = recf[seg+j+1], q2 = recf[seg+j+2], q3 = recf[seg+j+3];
        acc += h2f((u16)(q0 & 0xFFFFu)) * xs[(q0 >> 16) * 8 + L8];
        acc += h2f((u16)(q1 & 0xFFFFu)) * xs[(q1 >> 16) * 8 + L8];
        acc += h2f((u16)(q2 & 0xFFFFu)) * xs[(q2 >> 16) * 8 + L8];
        acc += h2f((u16)(q3 & 0xFFFFu)) * xs[(q3 >> 16) * 8 + L8];
      }
      for (; j < len; ++j) {
        u32 q = recf[seg + j];
        acc += h2f((u16)(q & 0xFFFFu)) * xs[(q >> 16) * 8 + L8];
      }
      aggh[r * 8 + L8] = f2h(acc);
    }
  }
  __syncthreads();

  // ---- 2 passes of 32 features ----
  for (int p = 0; p < 2; ++p) {
    // phase B: h1 slice from aggh regs
    for (int rr = t; rr < NN; rr += 1024) {
      uint4 av = *(const uint4*)(aggh + (size_t)rr * 8);
      float a[8];
      a[0] = h2f((u16)(av.x & 0xFFFFu)); a[1] = h2f((u16)(av.x >> 16));
      a[2] = h2f((u16)(av.y & 0xFFFFu)); a[3] = h2f((u16)(av.y >> 16));
      a[4] = h2f((u16)(av.z & 0xFFFFu)); a[5] = h2f((u16)(av.z >> 16));
      a[6] = h2f((u16)(av.w & 0xFFFFu)); a[7] = h2f((u16)(av.w >> 16));
      int orig = (int)(m2f[rr].x >> 16);
      float z[32];
      #pragma unroll
      for (int f = 0; f < 32; ++f) z[f] = t1f[p * 32 + f];
      #pragma unroll
      for (int k = 0; k < 8; ++k) {
        float fk = a[k];
        const float4* wr = (const float4*)(W1f + k * 64 + p * 32);
        #pragma unroll
        for (int q = 0; q < 8; ++q) {
          float4 w = wr[q];
          z[4*q]   += fk * w.x; z[4*q+1] += fk * w.y;
          z[4*q+2] += fk * w.z; z[4*q+3] += fk * w.w;
        }
      }
      u32 pk[16];
      #pragma unroll
      for (int q = 0; q < 16; ++q)
        pk[q] = pack2bf(fmaxf(z[2*q], 0.f), fmaxf(z[2*q+1], 0.f));
      u32 sw = ((u32)orig >> 1) & 3u;
      uint4* hp = (uint4*)(h1 + (size_t)orig * 32);
      hp[0 ^ sw] = make_uint4(pk[0],  pk[1],  pk[2],  pk[3]);
      hp[1 ^ sw] = make_uint4(pk[4],  pk[5],  pk[6],  pk[7]);
      hp[2 ^ sw] = make_uint4(pk[8],  pk[9],  pk[10], pk[11]);
      hp[3 ^ sw] = make_uint4(pk[12], pk[13], pk[14], pk[15]);
    }
    __syncthreads();

    // phase C: walk-2, 16-lane groups, 2 feats/lane
    {
      const int G16 = t >> 4, L16 = t & 15;
      // swizzled u32 offset within row: unit (L16>>2) ^ sw, sub (L16&3)
      u32* outp = (u32*)aggOut + (size_t)(g * 2 + p) * NN * 16;
      for (int c = 0; c < 32; ++c) {
        int r = c * 64 + G16;
        uint2 m = m2f[r];
        int orig = (int)(m.x >> 16), len = (int)(m.x & 0xFFFFu);
        u32 seg = m.y >> 16;
        float dv2 = h2f((u16)(m.y & 0xFFFFu));
#define H1W(S_) (*(const u32*)(h1 + (size_t)(S_) * 32 + (((((u32)(L16) >> 2) ^ (((u32)(S_) >> 1) & 3u)) * 4 + ((u32)(L16) & 3u)) * 2)))
        u32 hs = H1W((u32)orig);
        float a0 = dv2 * bflo(hs), a1 = dv2 * bfhi(hs);
        int j = 0;
        for (; j + 2 <= len; j += 2) {
          u32 qa = recf[seg + j], qb = recf[seg + j + 1];
          u32 ha = H1W(qa >> 16);
          float na = h2f((u16)(qa & 0xFFFFu));
          u32 hb = H1W(qb >> 16);
          float nb = h2f((u16)(qb & 0xFFFFu));
          a0 += na * bflo(ha); a1 += na * bfhi(ha);
          a0 += nb * bflo(hb); a1 += nb * bfhi(hb);
        }
        if (j < len) {
          u32 q = recf[seg + j];
          u32 hq = H1W(q >> 16);
          float nq = h2f((u16)(q & 0xFFFFu));
          a0 += nq * bflo(hq); a1 += nq * bfhi(hq);
        }
#undef H1W
        outp[(size_t)r * 16 + L16] = pack2bf(a0, a1);
      }
    }
    __syncthreads();
  }
}

// =========================================================================
// kW2p: one-shot prep — W2 -> bf16 W2bT[f][k] + BN2 fold; W1f = W1*s1, t1f.
// =========================================================================
__global__ void kW2p(const float* __restrict__ W2, const float* __restrict__ b2,
                     const float* __restrict__ g2, const float* __restrict__ be2,
                     const float* __restrict__ m2, const float* __restrict__ v2,
                     const float* __restrict__ W1, const float* __restrict__ b1,
                     const float* __restrict__ g1, const float* __restrict__ be1,
                     const float* __restrict__ m1, const float* __restrict__ v1,
                     u16* __restrict__ W2bT, float* __restrict__ scG, float* __restrict__ tcG,
                     float* __restrict__ W1f, float* __restrict__ t1f)
{
  const int t = threadIdx.x;    // 256
  for (int i = t; i < 4096; i += 256) {
    int f = i >> 6, k = i & 63;
    W2bT[i] = f2bf(W2[k * 64 + f]);
  }
  for (int i = t; i < 512; i += 256) {
    int f = i & 63;
    float sc = g1[f] * rsqrtf(v1[f] + EPS);
    W1f[i] = W1[i] * sc;
  }
  if (t < 64) {
    float sc2 = g2[t] * rsqrtf(v2[t] + EPS);
    scG[t] = sc2;
    tcG[t] = (b2[t] - m2[t]) * sc2 + be2[t];
    float sc1 = g1[t] * rsqrtf(v1[t] + EPS);
    t1f[t] = (b1[t] - m1[t]) * sc1 + be1[t];
  }
}

// =========================================================================
// kB: MFMA GEMM  C = agg2[2048x64](bf16, 2 half-planes) @ W2(bf16), fused
//     BN+ReLU+mean.  A/B frags share one k-slot bijection.
// =========================================================================
__global__ __launch_bounds__(512) void kB(
    const u16* __restrict__ agg, const u16* __restrict__ W2bT,
    const float* __restrict__ scG, const float* __restrict__ tcG,
    float* __restrict__ frames)
{
  __shared__ u16 W2s[4096];          // bf16 [f=64][k=64]
  __shared__ float part[8][64];
  const int g = blockIdx.x, tid = threadIdx.x;
  const int l = tid & 63, w = tid >> 6;
  const int lc = l & 15, lg = l >> 4;          // frag col / k-group

  ((uint4*)W2s)[tid] = ((const uint4*)W2bT)[tid];
  __syncthreads();

  short8 bfr[4][2];
  float scv[4], tcv[4];
  #pragma unroll
  for (int ct = 0; ct < 4; ++ct) {
    #pragma unroll
    for (int kt = 0; kt < 2; ++kt)
      bfr[ct][kt] = *(const short8*)(W2s + (ct * 16 + lc) * 64 + kt * 32 + lg * 8);
    scv[ct] = scG[ct * 16 + lc];
    tcv[ct] = tcG[ct * 16 + lc];
  }

  const u16* p0 = agg + (size_t)(g * 2 + 0) * NN * 32;   // k = 0..31
  const u16* p1 = agg + (size_t)(g * 2 + 1) * NN * 32;   // k = 32..63
  float fs0 = 0.f, fs1 = 0.f, fs2 = 0.f, fs3 = 0.f;

  for (int rti = 0; rti < 16; ++rti) {
    int arow = (w * 16 + rti) * 16 + lc;
    short8 a0 = *(const short8*)(p0 + (size_t)arow * 32 + lg * 8);
    short8 a1 = *(const short8*)(p1 + (size_t)arow * 32 + lg * 8);
#define CTILE(CT, FS) { \
    f32x4 acc = {0.f, 0.f, 0.f, 0.f}; \
    acc = __builtin_amdgcn_mfma_f32_16x16x32_bf16(a0, bfr[CT][0], acc, 0, 0, 0); \
    acc = __builtin_amdgcn_mfma_f32_16x16x32_bf16(a1, bfr[CT][1], acc, 0, 0, 0); \
    float s_ = fmaxf(acc[0] * scv[CT] + tcv[CT], 0.f) \
             + fmaxf(acc[1] * scv[CT] + tcv[CT], 0.f) \
             + fmaxf(acc[2] * scv[CT] + tcv[CT], 0.f) \
             + fmaxf(acc[3] * scv[CT] + tcv[CT], 0.f); \
    s_ += __shfl_xor(s_, 16); \
    s_ += __shfl_xor(s_, 32); \
    FS += s_; }
    CTILE(0, fs0) CTILE(1, fs1) CTILE(2, fs2) CTILE(3, fs3)
#undef CTILE
  }
  if (l < 16) {
    part[w][ 0 + l] = fs0;
    part[w][16 + l] = fs1;
    part[w][32 + l] = fs2;
    part[w][48 + l] = fs3;
  }
  __syncthreads();
  if (tid < 64) {
    float s = 0.f;
    #pragma unroll
    for (int q = 0; q < 8; ++q) s += part[q][tid];
    frames[g * 64 + tid] = s * (1.0f / 2048.0f);
  }
}

// =========================================================================
// kC: GRU over T=30 + classifier; one block per batch element
// =========================================================================
__global__ __launch_bounds__(384, 2) void kC(
    const float* __restrict__ frames,
    const float* __restrict__ Wih, const float* __restrict__ Whh,
    const float* __restrict__ bih, const float* __restrict__ bhh,
    const float* __restrict__ Wc1, const float* __restrict__ bc1,
    const float* __restrict__ Wc2, const float* __restrict__ bc2,
    float* __restrict__ out)
{
  const int b = blockIdx.x;
  const int j = threadIdx.x;     // 384 = 3*TEMP gate rows
  __shared__ float xt[64], h[128], GI[384], GH[384], hid[64];
  float wih[64], whh[128];
  const float4* wi4 = (const float4*)(Wih + (size_t)j * 64);
  #pragma unroll
  for (int q = 0; q < 16; ++q) { float4 v = wi4[q]; wih[4*q]=v.x; wih[4*q+1]=v.y; wih[4*q+2]=v.z; wih[4*q+3]=v.w; }
  const float4* wh4 = (const float4*)(Whh + (size_t)j * 128);
  #pragma unroll
  for (int q = 0; q < 32; ++q) { float4 v = wh4[q]; whh[4*q]=v.x; whh[4*q+1]=v.y; whh[4*q+2]=v.z; whh[4*q+3]=v.w; }
  float bi = bih[j], bh = bhh[j];
  if (j < 128) h[j] = 0.f;
  __syncthreads();
  for (int t = 0; t < T_; ++t) {
    if (j < 64) xt[j] = frames[((size_t)b * T_ + t) * 64 + j];
    __syncthreads();
    float gi = bi, gh = bh;
    #pragma unroll
    for (int k = 0; k < 64; ++k) gi += xt[k] * wih[k];
    #pragma unroll
    for (int k = 0; k < 128; ++k) gh += h[k] * whh[k];
    GI[j] = gi; GH[j] = gh;
    __syncthreads();
    if (j < 128) {
      float r = 1.f / (1.f + __expf(-(GI[j] + GH[j])));
      float z = 1.f / (1.f + __expf(-(GI[128 + j] + GH[128 + j])));
      float n = tanhf(GI[256 + j] + r * GH[256 + j]);
      h[j] = (1.f - z) * n + z * h[j];
    }
    __syncthreads();
  }
  if (j < 64) {
    float a = bc1[j];
    #pragma unroll 4
    for (int k = 0; k < 128; ++k) a += h[k] * Wc1[k * 64 + j];
    hid[j] = fmaxf(a, 0.f);
  }
  __syncthreads();
  if (j < 2) {
    float o = bc2[j];
    #pragma unroll
    for (int k = 0; k < 64; ++k) o += hid[k] * Wc2[k * 2 + j];
    out[b * 2 + j] = o;
  }
}

// ---------- launch ----------
extern "C" void kernel_launch(void* const* d_in, const int* in_sizes, int n_in,
                              void* d_out, int out_size, void* d_ws, size_t ws_size,
                              hipStream_t stream) {
  const float* x   = (const float*)d_in[0];
  const int*   ei  = (const int*)d_in[1];
  const float* ew  = (const float*)d_in[2];
  const int*   nid = (const int*)d_in[3];
  const float* W1  = (const float*)d_in[4];
  const float* b1  = (const float*)d_in[5];
  const float* W2  = (const float*)d_in[6];
  const float* b2  = (const float*)d_in[7];
  const float* g1  = (const float*)d_in[8];
  const float* be1 = (const float*)d_in[9];
  const float* m1  = (const float*)d_in[10];
  const float* v1  = (const float*)d_in[11];
  const float* g2  = (const float*)d_in[12];
  const float* be2 = (const float*)d_in[13];
  const float* m2  = (const float*)d_in[14];
  const float* v2  = (const float*)d_in[15];
  const float* Wih = (const float*)d_in[16];
  const float* Whh = (const float*)d_in[17];
  const float* bih = (const float*)d_in[18];
  const float* bhh = (const float*)d_in[19];
  const float* Wc1 = (const float*)d_in[20];
  const float* bc1 = (const float*)d_in[21];
  const float* Wc2 = (const float*)d_in[22];
  const float* bc2 = (const float*)d_in[23];
  float* out = (float*)d_out;

  // workspace layout (bytes), total 196,741,888 (< proven 198.7MB)
  const size_t REC_OFF   = 0;                    // 62,914,560
  const size_t PL_OFF    = 62914560;             // agg2 2 half-planes bf16: 125,829,120
  const size_t META_OFF  = 188743680;            // uint2[480*2048] = 7,864,320
  const size_t PREP_OFF  = 196608000;            // W2bT 8192 | scG 256 | tcG 256 | W1f 2048 | t1f 256
  const size_t FR_OFF    = 196619008;            // 122,880
  if (ws_size < (size_t)196741888) return;

  u32*   rec   = (u32*)((char*)d_ws + REC_OFF);
  u16*   agg2  = (u16*)((char*)d_ws + PL_OFF);
  u32*   meta2 = (u32*)((char*)d_ws + META_OFF);
  u16*   W2bT  = (u16*)((char*)d_ws + PREP_OFF);
  float* scG   = (float*)((char*)d_ws + PREP_OFF + 8192);
  float* tcG   = (float*)((char*)d_ws + PREP_OFF + 8448);
  float* W1f   = (float*)((char*)d_ws + PREP_OFF + 8704);
  float* t1f   = (float*)((char*)d_ws + PREP_OFF + 10752);
  float* frm   = (float*)((char*)d_ws + FR_OFF);

  hipFuncSetAttribute((const void*)kPre,  hipFuncAttributeMaxDynamicSharedMemorySize, KP_LDS);
  hipFuncSetAttribute((const void*)kFuse, hipFuncAttributeMaxDynamicSharedMemorySize, KF_LDS);

  kW2p<<<1, 256, 0, stream>>>(W2, b2, g2, be2, m2, v2,
                              W1, b1, g1, be1, m1, v1,
                              W2bT, scG, tcG, W1f, t1f);
  kPre<<<NF, 1024, KP_LDS, stream>>>(ei, ew, nid, rec, meta2);
  kFuse<<<NF, 1024, KF_LDS, stream>>>(x, rec, (const uint2*)meta2, W1f, t1f, agg2);
  kB<<<NF, 512, 0, stream>>>(agg2, W2bT, scG, tcG, frm);
  kC<<<B_, 384, 0, stream>>>(frm, Wih, Whh, bih, bhh, Wc1, bc1, Wc2, bc2, out);
}

// Round 9
// 466.931 us; speedup vs baseline: 1.6462x; 1.6462x over previous
//
#include <hip/hip_runtime.h>
#include <hip/hip_fp16.h>
#include <stdint.h>

#define B_   16
#define T_   30
#define NF   480       // frames = B*T
#define NN   2048      // nodes
#define EE   32768     // edges
#define EPS  1e-5f

typedef unsigned int u32;
typedef unsigned short u16;
typedef __attribute__((ext_vector_type(8))) short short8;   // 8 bf16 = 4 VGPR
typedef __attribute__((ext_vector_type(4))) float f32x4;    // MFMA C/D frag

// ---------- helpers ----------
__device__ __forceinline__ u16 f2bf(float f) {           // RNE f32->bf16
  u32 u = __float_as_uint(f);
  u32 r = u + 0x7FFFu + ((u >> 16) & 1u);
  return (u16)(r >> 16);
}
__device__ __forceinline__ u32 pack2bf(float a, float b) {
  return (u32)f2bf(a) | ((u32)f2bf(b) << 16);
}
__device__ __forceinline__ float bflo(u32 w) { return __uint_as_float(w << 16); }
__device__ __forceinline__ float bfhi(u32 w) { return __uint_as_float(w & 0xFFFF0000u); }
__device__ __forceinline__ u16 f2h(float f) { return __half_as_ushort(__float2half(f)); }
__device__ __forceinline__ float h2f(u16 h) { return __half2float(__ushort_as_half(h)); }
__device__ __forceinline__ u32 pack2h(float a, float b) {
  return (u32)f2h(a) | ((u32)f2h(b) << 16);
}

// =========================================================================
// kPre: sort node_ids -> perm; degrees; rank dsts by length (desc, exact
//       per-length buckets); JDS offsets; counting-sort edges into JDS
//       layout in LDS (src = ORIG x-row); coalesced stream-out.
// =========================================================================
#define KP_KEYS 0          // u32[2048] (dead before rec overlay)
#define KP_HIST 8192       // u32[256]  (scan scratch; dead before overlay)
#define KP_CUM  9216       // u32[256]
#define KP_CUR  10240      // u32[256]
#define KP_REC  0          // overlay u32[32768] = 131072 B
#define KP_DINV 131072     // f32[2048]
#define KP_CNT  139264     // u32[2048]
#define KP_PERM 147456     // u16[2048]
#define KP_RANK 151552     // u16[2048]
#define KP_OFF  155648     // u32[256]
#define KP_LDS  156672

__global__ __launch_bounds__(1024) void kPre(
    const int* __restrict__ ei, const float* __restrict__ ew, const int* __restrict__ nid,
    u32* __restrict__ recG, u32* __restrict__ metaG, float* __restrict__ dv2G,
    u32* __restrict__ offG)
{
  extern __shared__ unsigned char smem[];
  const int g = blockIdx.x, t = threadIdx.x;
  const int*   eig  = ei  + (size_t)g * 2 * EE;
  const float* ewg  = ew  + (size_t)g * EE;
  const int*   nidg = nid + (size_t)g * NN;

  u32*  keys = (u32*)(smem + KP_KEYS);
  u32*  hist = (u32*)(smem + KP_HIST);
  u32*  cum  = (u32*)(smem + KP_CUM);
  u32*  cur  = (u32*)(smem + KP_CUR);
  u32*  rec  = (u32*)(smem + KP_REC);
  float* dinv = (float*)(smem + KP_DINV);
  u32*  cnt  = (u32*)(smem + KP_CNT);
  u16*  perm = (u16*)(smem + KP_PERM);
  u16*  rank = (u16*)(smem + KP_RANK);
  u32*  off  = (u32*)(smem + KP_OFF);

  // keys (stable sort: key = nid<<11 | idx), init dinv/cnt
  keys[t]        = ((u32)nidg[t] << 11) | (u32)t;
  keys[t + 1024] = ((u32)nidg[t + 1024] << 11) | (u32)(t + 1024);
  dinv[t] = 1.0f; dinv[t + 1024] = 1.0f;
  cnt[t] = 0u; cnt[t + 1024] = 0u;
  __syncthreads();

  // bitonic sort, 1 pair/thread/pass
  for (int k = 2; k <= NN; k <<= 1) {
    for (int j = k >> 1; j > 0; j >>= 1) {
      int i = ((t & ~(j - 1)) << 1) | (t & (j - 1));
      int l = i | j;
      u32 x = keys[i], y = keys[l];
      bool up = ((i & k) == 0);
      if ((x > y) == up) { keys[i] = y; keys[l] = x; }
      __syncthreads();
    }
  }
  perm[2*t]   = (u16)(keys[2*t] & 2047u);
  perm[2*t+1] = (u16)(keys[2*t+1] & 2047u);

  // degree (self-loop weight 1) + per-dst edge count
  for (int e = t; e < EE; e += 1024) {
    int d = eig[EE + e];
    atomicAdd(&dinv[d], ewg[e]);
    atomicAdd(&cnt[d], 1u);
  }
  __syncthreads();
  dinv[2*t]   = rsqrtf(dinv[2*t]);
  dinv[2*t+1] = rsqrtf(dinv[2*t+1]);

  // ---- length histogram (256 buckets) ----
  if (t < 256) hist[t] = 0u;
  __syncthreads();
  for (int i = t; i < NN; i += 1024) {
    u32 L = cnt[i];
    atomicAdd(&hist[L < 255u ? L : 255u], 1u);
  }
  __syncthreads();
  if (t < 256) cum[t] = hist[t];
  __syncthreads();
  for (int o = 1; o < 256; o <<= 1) {
    u32 v = 0u;
    if (t < 256 && t >= o) v = cum[t - o];
    __syncthreads();
    if (t < 256) cum[t] += v;
    __syncthreads();
  }
  // cntgt[b] = #len > b ; cur = bucket start (descending order)
  if (t < 256) cur[t] = (u32)NN - cum[t];
  __syncthreads();
  // off = exclusive prefix of cntgt (reuse hist as scan buffer)
  if (t < 256) hist[t] = cur[t];
  __syncthreads();
  for (int o = 1; o < 256; o <<= 1) {
    u32 v = 0u;
    if (t < 256 && t >= o) v = hist[t - o];
    __syncthreads();
    if (t < 256) hist[t] += v;
    __syncthreads();
  }
  if (t < 256) {
    u32 ov = hist[t] - cur[t];
    off[t] = ov;
    offG[(size_t)g * 256 + t] = ov;
  }
  __syncthreads();

  // ---- rank assignment (desc length) ----
  for (int i = t; i < NN; i += 1024) {
    u32 L = cnt[i];
    u32 b = L < 255u ? L : 255u;
    u32 r = atomicAdd(&cur[b], 1u);
    rank[i] = (u16)r;
    metaG[(size_t)g * NN + r] = ((u32)perm[i] << 16) | (L & 0xFFFFu);
    float dv = dinv[i];
    dv2G[(size_t)g * NN + r] = dv * dv;
  }
  __syncthreads();
  // reset cnt as per-dst cursor
  cnt[t] = 0u; cnt[t + 1024] = 0u;
  __syncthreads();   // keys/hist/cum/cur dead -> rec overlays [0,131072)

  // ---- counting-sort edges into JDS: rec[off[k] + rank[d]] ----
  for (int e = t; e < EE; e += 1024) {
    int s = eig[e], d = eig[EE + e];
    float nrm = dinv[s] * ewg[e] * dinv[d];
    u32 k = atomicAdd(&cnt[d], 1u);
    u32 pos = off[k] + (u32)rank[d];
    rec[pos] = ((u32)perm[s] << 11) | (u32)(f2h(nrm) >> 5) | ((u32)f2h(nrm) << 27);
    // NOTE: we keep the simple encoding below instead (src<<16 | f16):
    rec[pos] = ((u32)perm[s] << 16) | (u32)f2h(nrm);
  }
  __syncthreads();

  // coalesced stream-out
  uint4* rg = (uint4*)(recG + (size_t)g * EE);
  const uint4* rl = (const uint4*)rec;
  for (int i = t; i < EE / 4; i += 1024) rg[i] = rl[i];
}

// =========================================================================
// kFuse v5: thread-per-rank JDS walks; h1 in LDS as f16[2048][32] (64B
//   rows, 128KB) -> TWO passes of 32 features (rec read 3x total).
//   A: walk-1 over x (xs f32[2048][8] in LDS) -> agg[2][8] in regs.
//   Per pass p: B: h1 slice = ReLU(agg@W1f + t1f) feats p*32.. -> LDS,
//      16B units XOR-swizzled by (orig>>1)&3  (full 8-slot coverage:
//      slot = 4*(orig&1) + u^((orig>>1)&3) hits all 8 as orig&7 varies).
//   C: walk-2 acc[32] regs -> 4 unit-planes (16B-row contiguous stores).
//   1024 thr, 134.4KB LDS, launch_bounds(1024,4).
// =========================================================================
#define KF_H1   0        // A: xs f32[2048][8] (64KB); B/C: h1 f16[2048][32] (128KB)
#define KF_W1   131072   // f32[512]
#define KF_T1   133120   // f32[64]
#define KF_OFF  133376   // u32[256]
#define KF_LDS  134400

__global__ __launch_bounds__(1024, 4) void kFuse(
    const float* __restrict__ x, const u32* __restrict__ recG,
    const u32* __restrict__ metaG, const float* __restrict__ dv2G,
    const u32* __restrict__ offG,
    const float* __restrict__ W1f, const float* __restrict__ t1f,
    u16* __restrict__ aggOut)
{
  extern __shared__ unsigned char smem[];
  float* xs  = (float*)smem;                  // phase A
  u16*  h1   = (u16*)smem;                    // phases B/C: [2048][32] f16
  float* W1s = (float*)(smem + KF_W1);
  float* t1s = (float*)(smem + KF_T1);
  u32*  offL = (u32*)(smem + KF_OFF);
  const int g = blockIdx.x, t = threadIdx.x;
  const u32* recf = recG + (size_t)g * EE;

  // stage x rows (orig order, coalesced) + constants
  {
    const float4* xg = (const float4*)(x + (size_t)g * NN * 8);
    for (int i = t; i < NN * 2; i += 1024) ((float4*)xs)[i] = xg[i];
  }
  if (t < 512) W1s[t] = W1f[t];
  if (t < 64) t1s[t] = t1f[t];
  if (t >= 512 && t < 768) offL[t - 512] = offG[(size_t)g * 256 + (t - 512)];

  // per-rank meta (rank-major, coalesced)
  u32 origA[2], lenA[2]; float dvA[2];
  #pragma unroll
  for (int it = 0; it < 2; ++it) {
    u32 r = (u32)(it * 1024 + t);
    u32 m = metaG[(size_t)g * NN + r];
    origA[it] = m >> 16; lenA[it] = m & 0xFFFFu;
    dvA[it] = dv2G[(size_t)g * NN + r];
  }
  __syncthreads();

  // ---- phase A: walk-1 in 8-dim x space, agg stays in registers ----
  float agg[2][8];
#define P1(RC) { u32 rc_ = (RC); u32 s_ = rc_ >> 16; \
    float nm_ = h2f((u16)(rc_ & 0xFFFFu)); \
    const float4* xp_ = (const float4*)(smem + (size_t)s_ * 32); \
    float4 a_ = xp_[0], b_ = xp_[1]; \
    ac0 += nm_*a_.x; ac1 += nm_*a_.y; ac2 += nm_*a_.z; ac3 += nm_*a_.w; \
    ac4 += nm_*b_.x; ac5 += nm_*b_.y; ac6 += nm_*b_.z; ac7 += nm_*b_.w; }
  #pragma unroll
  for (int it = 0; it < 2; ++it) {
    u32 r = (u32)(it * 1024 + t);
    float ac0=0,ac1=0,ac2=0,ac3=0,ac4=0,ac5=0,ac6=0,ac7=0;
    int len = (int)lenA[it];
    int j = 0;
    for (; j + 4 <= len; j += 4) {       // JDS: lane-contiguous rec reads
      u32 o0 = offL[j], o1 = offL[j+1], o2 = offL[j+2], o3 = offL[j+3];
      u32 q0 = recf[o0 + r], q1 = recf[o1 + r], q2 = recf[o2 + r], q3 = recf[o3 + r];
      P1(q0) P1(q1) P1(q2) P1(q3)
    }
    for (; j < len; ++j) { P1(recf[offL[j] + r]) }
    {  // self-loop (dv = dinv^2)
      const float4* xd = (const float4*)(smem + (size_t)origA[it] * 32);
      float4 a = xd[0], b = xd[1];
      float dv = dvA[it];
      ac0 += dv*a.x; ac1 += dv*a.y; ac2 += dv*a.z; ac3 += dv*a.w;
      ac4 += dv*b.x; ac5 += dv*b.y; ac6 += dv*b.z; ac7 += dv*b.w;
    }
    agg[it][0]=ac0; agg[it][1]=ac1; agg[it][2]=ac2; agg[it][3]=ac3;
    agg[it][4]=ac4; agg[it][5]=ac5; agg[it][6]=ac6; agg[it][7]=ac7;
  }
#undef P1

  // ---- 2 passes x 32 features ----
  for (int p = 0; p < 2; ++p) {
    __syncthreads();   // pass 0: xs dead; pass 1: previous h1 readers done

    // phase B: h1 slice (feats p*32..p*32+31) from registers, f16, swizzled
    #pragma unroll
    for (int it = 0; it < 2; ++it) {
      float z[32];
      #pragma unroll
      for (int f = 0; f < 32; ++f) z[f] = t1s[p * 32 + f];
      #pragma unroll
      for (int k = 0; k < 8; ++k) {
        float fk = agg[it][k];
        const float4* wr = (const float4*)(W1s + k * 64 + p * 32);
        #pragma unroll
        for (int q = 0; q < 8; ++q) {
          float4 w = wr[q];
          z[4*q]   += fk * w.x; z[4*q+1] += fk * w.y;
          z[4*q+2] += fk * w.z; z[4*q+3] += fk * w.w;
        }
      }
      u32 orig = origA[it];
      u32 sw = (orig >> 1) & 3u;
      uint4* hp = (uint4*)(h1 + (size_t)orig * 32);
      #pragma unroll
      for (int u = 0; u < 4; ++u) {
        int b = u * 8;
        uint4 v = make_uint4(
          pack2h(fmaxf(z[b],   0.f), fmaxf(z[b+1], 0.f)),
          pack2h(fmaxf(z[b+2], 0.f), fmaxf(z[b+3], 0.f)),
          pack2h(fmaxf(z[b+4], 0.f), fmaxf(z[b+5], 0.f)),
          pack2h(fmaxf(z[b+6], 0.f), fmaxf(z[b+7], 0.f)));
        hp[u ^ sw] = v;
      }
    }
    __syncthreads();

    // phase C: walk-2, 32 feats, acc in regs
#define ROWACC(SRC, NM, OP) { u32 s_ = (SRC); float nm_ = (NM); \
    u32 sw_ = (s_ >> 1) & 3u; \
    const uint4* rp_ = (const uint4*)(h1 + (size_t)s_ * 32); \
    _Pragma("unroll") \
    for (int u = 0; u < 4; ++u) { \
      uint4 w_ = rp_[u ^ sw_]; \
      int b_ = u * 8; \
      acc[b_+0] OP nm_ * h2f((u16)(w_.x & 0xFFFFu)); \
      acc[b_+1] OP nm_ * h2f((u16)(w_.x >> 16)); \
      acc[b_+2] OP nm_ * h2f((u16)(w_.y & 0xFFFFu)); \
      acc[b_+3] OP nm_ * h2f((u16)(w_.y >> 16)); \
      acc[b_+4] OP nm_ * h2f((u16)(w_.z & 0xFFFFu)); \
      acc[b_+5] OP nm_ * h2f((u16)(w_.z >> 16)); \
      acc[b_+6] OP nm_ * h2f((u16)(w_.w & 0xFFFFu)); \
      acc[b_+7] OP nm_ * h2f((u16)(w_.w >> 16)); \
    } }

    for (int it = 0; it < 2; ++it) {
      u32 r = (u32)(it * 1024 + t);
      float acc[32];
      ROWACC(origA[it], dvA[it], =)      // self-loop initializes acc
      int len = (int)lenA[it];
      for (int j = 0; j < len; ++j) {
        u32 q = recf[offL[j] + r];
        ROWACC(q >> 16, h2f((u16)(q & 0xFFFFu)), +=)
      }
      // pass p -> unit-planes p*4..p*4+3 (feats p*32+u*8..+7), 16B/lane
      #pragma unroll
      for (int u = 0; u < 4; ++u) {
        int b = u * 8;
        uint4 o = make_uint4(
          pack2bf(acc[b],   acc[b+1]), pack2bf(acc[b+2], acc[b+3]),
          pack2bf(acc[b+4], acc[b+5]), pack2bf(acc[b+6], acc[b+7]));
        *((uint4*)aggOut + ((size_t)(g * 8 + p * 4 + u)) * NN + r) = o;
      }
    }
#undef ROWACC
  }
}

// =========================================================================
// kW2p: one-shot prep — W2 -> bf16 W2bT[f][k] + BN2 fold; W1f = W1*s1, t1f.
// =========================================================================
__global__ void kW2p(const float* __restrict__ W2, const float* __restrict__ b2,
                     const float* __restrict__ g2, const float* __restrict__ be2,
                     const float* __restrict__ m2, const float* __restrict__ v2,
                     const float* __restrict__ W1, const float* __restrict__ b1,
                     const float* __restrict__ g1, const float* __restrict__ be1,
                     const float* __restrict__ m1, const float* __restrict__ v1,
                     u16* __restrict__ W2bT, float* __restrict__ scG, float* __restrict__ tcG,
                     float* __restrict__ W1f, float* __restrict__ t1f)
{
  const int t = threadIdx.x;    // 256
  for (int i = t; i < 4096; i += 256) {
    int f = i >> 6, k = i & 63;
    W2bT[i] = f2bf(W2[k * 64 + f]);
  }
  for (int i = t; i < 512; i += 256) {
    int f = i & 63;
    float sc = g1[f] * rsqrtf(v1[f] + EPS);
    W1f[i] = W1[i] * sc;
  }
  if (t < 64) {
    float sc2 = g2[t] * rsqrtf(v2[t] + EPS);
    scG[t] = sc2;
    tcG[t] = (b2[t] - m2[t]) * sc2 + be2[t];
    float sc1 = g1[t] * rsqrtf(v1[t] + EPS);
    t1f[t] = (b1[t] - m1[t]) * sc1 + be1[t];
  }
}

// =========================================================================
// kB: MFMA GEMM  C = agg2[2048x64](bf16, 8 unit-planes) @ W2(bf16), fused
//     BN+ReLU+mean.  A/B frags share one k-slot bijection.
// =========================================================================
__global__ __launch_bounds__(512) void kB(
    const u16* __restrict__ agg, const u16* __restrict__ W2bT,
    const float* __restrict__ scG, const float* __restrict__ tcG,
    float* __restrict__ frames)
{
  __shared__ u16 W2s[4096];          // bf16 [f=64][k=64]
  __shared__ float part[8][64];
  const int g = blockIdx.x, tid = threadIdx.x;
  const int l = tid & 63, w = tid >> 6;
  const int lc = l & 15, lg = l >> 4;          // frag col / k-group

  ((uint4*)W2s)[tid] = ((const uint4*)W2bT)[tid];
  __syncthreads();

  short8 bfr[4][2];
  float scv[4], tcv[4];
  #pragma unroll
  for (int ct = 0; ct < 4; ++ct) {
    #pragma unroll
    for (int kt = 0; kt < 2; ++kt)
      bfr[ct][kt] = *(const short8*)(W2s + (ct * 16 + lc) * 64 + kt * 32 + lg * 8);
    scv[ct] = scG[ct * 16 + lc];
    tcv[ct] = tcG[ct * 16 + lc];
  }

  const u16* base = agg + (size_t)g * (8 * NN * 8);   // 8 unit-planes x NN x 8 u16
  float fs0 = 0.f, fs1 = 0.f, fs2 = 0.f, fs3 = 0.f;

  for (int rti = 0; rti < 16; ++rti) {
    int arow = (w * 16 + rti) * 16 + lc;
    short8 a0 = *(const short8*)(base + ((size_t)(0 * 4 + lg) * NN + arow) * 8);
    short8 a1 = *(const short8*)(base + ((size_t)(1 * 4 + lg) * NN + arow) * 8);
#define CTILE(CT, FS) { \
    f32x4 acc = {0.f, 0.f, 0.f, 0.f}; \
    acc = __builtin_amdgcn_mfma_f32_16x16x32_bf16(a0, bfr[CT][0], acc, 0, 0, 0); \
    acc = __builtin_amdgcn_mfma_f32_16x16x32_bf16(a1, bfr[CT][1], acc, 0, 0, 0); \
    float s_ = fmaxf(acc[0] * scv[CT] + tcv[CT], 0.f) \
             + fmaxf(acc[1] * scv[CT] + tcv[CT], 0.f) \
             + fmaxf(acc[2] * scv[CT] + tcv[CT], 0.f) \
             + fmaxf(acc[3] * scv[CT] + tcv[CT], 0.f); \
    s_ += __shfl_xor(s_, 16); \
    s_ += __shfl_xor(s_, 32); \
    FS += s_; }
    CTILE(0, fs0) CTILE(1, fs1) CTILE(2, fs2) CTILE(3, fs3)
#undef CTILE
  }
  if (l < 16) {
    part[w][ 0 + l] = fs0;
    part[w][16 + l] = fs1;
    part[w][32 + l] = fs2;
    part[w][48 + l] = fs3;
  }
  __syncthreads();
  if (tid < 64) {
    float s = 0.f;
    #pragma unroll
    for (int q = 0; q < 8; ++q) s += part[q][tid];
    frames[g * 64 + tid] = s * (1.0f / 2048.0f);
  }
}

// =========================================================================
// kC: GRU over T=30 + classifier; one block per batch element
// =========================================================================
__global__ __launch_bounds__(384, 2) void kC(
    const float* __restrict__ frames,
    const float* __restrict__ Wih, const float* __restrict__ Whh,
    const float* __restrict__ bih, const float* __restrict__ bhh,
    const float* __restrict__ Wc1, const float* __restrict__ bc1,
    const float* __restrict__ Wc2, const float* __restrict__ bc2,
    float* __restrict__ out)
{
  const int b = blockIdx.x;
  const int j = threadIdx.x;     // 384 = 3*TEMP gate rows
  __shared__ float xt[64], h[128], GI[384], GH[384], hid[64];
  float wih[64], whh[128];
  const float4* wi4 = (const float4*)(Wih + (size_t)j * 64);
  #pragma unroll
  for (int q = 0; q < 16; ++q) { float4 v = wi4[q]; wih[4*q]=v.x; wih[4*q+1]=v.y; wih[4*q+2]=v.z; wih[4*q+3]=v.w; }
  const float4* wh4 = (const float4*)(Whh + (size_t)j * 128);
  #pragma unroll
  for (int q = 0; q < 32; ++q) { float4 v = wh4[q]; whh[4*q]=v.x; whh[4*q+1]=v.y; whh[4*q+2]=v.z; whh[4*q+3]=v.w; }
  float bi = bih[j], bh = bhh[j];
  if (j < 128) h[j] = 0.f;
  __syncthreads();
  for (int t = 0; t < T_; ++t) {
    if (j < 64) xt[j] = frames[((size_t)b * T_ + t) * 64 + j];
    __syncthreads();
    float gi = bi, gh = bh;
    #pragma unroll
    for (int k = 0; k < 64; ++k) gi += xt[k] * wih[k];
    #pragma unroll
    for (int k = 0; k < 128; ++k) gh += h[k] * whh[k];
    GI[j] = gi; GH[j] = gh;
    __syncthreads();
    if (j < 128) {
      float r = 1.f / (1.f + __expf(-(GI[j] + GH[j])));
      float z = 1.f / (1.f + __expf(-(GI[128 + j] + GH[128 + j])));
      float n = tanhf(GI[256 + j] + r * GH[256 + j]);
      h[j] = (1.f - z) * n + z * h[j];
    }
    __syncthreads();
  }
  if (j < 64) {
    float a = bc1[j];
    #pragma unroll 4
    for (int k = 0; k < 128; ++k) a += h[k] * Wc1[k * 64 + j];
    hid[j] = fmaxf(a, 0.f);
  }
  __syncthreads();
  if (j < 2) {
    float o = bc2[j];
    #pragma unroll
    for (int k = 0; k < 64; ++k) o += hid[k] * Wc2[k * 2 + j];
    out[b * 2 + j] = o;
  }
}

// ---------- launch ----------
extern "C" void kernel_launch(void* const* d_in, const int* in_sizes, int n_in,
                              void* d_out, int out_size, void* d_ws, size_t ws_size,
                              hipStream_t stream) {
  const float* x   = (const float*)d_in[0];
  const int*   ei  = (const int*)d_in[1];
  const float* ew  = (const float*)d_in[2];
  const int*   nid = (const int*)d_in[3];
  const float* W1  = (const float*)d_in[4];
  const float* b1  = (const float*)d_in[5];
  const float* W2  = (const float*)d_in[6];
  const float* b2  = (const float*)d_in[7];
  const float* g1  = (const float*)d_in[8];
  const float* be1 = (const float*)d_in[9];
  const float* m1  = (const float*)d_in[10];
  const float* v1  = (const float*)d_in[11];
  const float* g2  = (const float*)d_in[12];
  const float* be2 = (const float*)d_in[13];
  const float* m2  = (const float*)d_in[14];
  const float* v2  = (const float*)d_in[15];
  const float* Wih = (const float*)d_in[16];
  const float* Whh = (const float*)d_in[17];
  const float* bih = (const float*)d_in[18];
  const float* bhh = (const float*)d_in[19];
  const float* Wc1 = (const float*)d_in[20];
  const float* bc1 = (const float*)d_in[21];
  const float* Wc2 = (const float*)d_in[22];
  const float* bc2 = (const float*)d_in[23];
  float* out = (float*)d_out;

  // workspace layout (bytes), total ~197.2MB (< proven 198.7MB)
  const size_t REC_OFF   = 0;                    // 62,914,560
  const size_t PL_OFF    = 62914560;             // agg2 8 unit-planes bf16: 125,829,120
  const size_t META_OFF  = 188743680;            // u32[480*2048] = 3,932,160
  const size_t DV2_OFF   = 192675840;            // f32[480*2048] = 3,932,160
  const size_t OFF_OFF   = 196608000;            // u32[480*256] = 491,520
  const size_t PREP_OFF  = 197099520;            // W2bT 8192 | scG 256 | tcG 256 | W1f 2048 | t1f 256
  const size_t FR_OFF    = 197110528;            // 122,880
  if (ws_size < (size_t)197233408) return;

  u32*   rec   = (u32*)((char*)d_ws + REC_OFF);
  u16*   agg2  = (u16*)((char*)d_ws + PL_OFF);
  u32*   metaG = (u32*)((char*)d_ws + META_OFF);
  float* dv2G  = (float*)((char*)d_ws + DV2_OFF);
  u32*   offG  = (u32*)((char*)d_ws + OFF_OFF);
  u16*   W2bT  = (u16*)((char*)d_ws + PREP_OFF);
  float* scG   = (float*)((char*)d_ws + PREP_OFF + 8192);
  float* tcG   = (float*)((char*)d_ws + PREP_OFF + 8448);
  float* W1f   = (float*)((char*)d_ws + PREP_OFF + 8704);
  float* t1f   = (float*)((char*)d_ws + PREP_OFF + 10752);
  float* frm   = (float*)((char*)d_ws + FR_OFF);

  hipFuncSetAttribute((const void*)kPre,  hipFuncAttributeMaxDynamicSharedMemorySize, KP_LDS);
  hipFuncSetAttribute((const void*)kFuse, hipFuncAttributeMaxDynamicSharedMemorySize, KF_LDS);

  kW2p<<<1, 256, 0, stream>>>(W2, b2, g2, be2, m2, v2,
                              W1, b1, g1, be1, m1, v1,
                              W2bT, scG, tcG, W1f, t1f);
  kPre<<<NF, 1024, KP_LDS, stream>>>(ei, ew, nid, rec, metaG, dv2G, offG);
  kFuse<<<NF, 1024, KF_LDS, stream>>>(x, rec, metaG, dv2G, offG, W1f, t1f, agg2);
  kB<<<NF, 512, 0, stream>>>(agg2, W2bT, scG, tcG, frm);
  kC<<<B_, 384, 0, stream>>>(frm, Wih, Whh, bih, bhh, Wc1, bc1, Wc2, bc2, out);
}